// Round 5
// baseline (748.927 us; speedup 1.0000x reference)
//
#include <hip/hip_runtime.h>

// BERT encoder block fwd. R5: persistent-block GEMM — grid=256, each block walks
// multiple 256x256 output tiles with a CONTINUOUS staging pipeline across tile
// boundaries (prologue paid once per block, epilogue overlapped with next tile's
// in-flight loads). Core schedule per K-tile unchanged from R3/R4 (8-phase-family:
// 4 phases, T2 XOR swizzle, counted vmcnt(4), T5 setprio, T1 XCD swizzle).
// Also fixes R4 bug: PV row-normalization now uses linv[z*M + row] (was batch-0 only).

typedef __attribute__((ext_vector_type(4))) float  f32x4;
typedef __attribute__((ext_vector_type(8))) short  s16x8;
typedef __attribute__((ext_vector_type(4))) short  s16x4;
typedef unsigned short u16;
typedef unsigned int   u32;

__device__ __forceinline__ float bf2f(short s) {
  u32 u = ((u32)(u16)s) << 16;
  float f; __builtin_memcpy(&f, &u, 4); return f;
}
__device__ __forceinline__ short f2bf(float f) {
  u32 u; __builtin_memcpy(&u, &f, 4);
  u32 r = (u + 0x7fffu + ((u >> 16) & 1u)) >> 16;   // RNE
  return (short)(u16)r;
}

// async global->LDS, 16B/lane; LDS dest must be wave-uniform base + lane*16
__device__ __forceinline__ void gload16(const void* g, void* l) {
  __builtin_amdgcn_global_load_lds(
      (const __attribute__((address_space(1))) u32*)g,
      (__attribute__((address_space(3))) u32*)l, 16, 0, 0);
}

// stage one 128-row half of a 256x64 bf16 tile (2 gload16/thread, 512 threads)
__device__ __forceinline__ void stage_half(const char* gop, long long ldb,
                                           long long rowbase, int tt, int h,
                                           u16* ldsop, int tid) {
#pragma unroll
  for (int l = 0; l < 2; ++l) {
    const int o   = (l * 512 + tid) * 16;          // linear byte offset in half (16 KiB)
    const int rih = o >> 7;                        // row in half 0..127
    const int scb = (o & 127) ^ ((rih & 7) << 4);  // inverse-swizzled source col-byte
    gload16(gop + (rowbase + h * 128 + rih) * ldb + (long long)tt * 128 + scb,
            (char*)ldsop + h * 16384 + o);
  }
}

#define RD_A(MH) do { _Pragma("unroll") for (int mi = 0; mi < 4; ++mi) { \
    const int row_ = wm * 64 + (MH) * 128 + mi * 16 + lr; \
    const int sw_ = (row_ & 7) << 4; const int rb_ = row_ << 7; \
    _Pragma("unroll") for (int kk = 0; kk < 2; ++kk) \
      af[mi][kk] = *(const s16x8*)(pa + rb_ + (((kk << 6) | (kg << 4)) ^ sw_)); } } while (0)

#define RD_B(NH) do { _Pragma("unroll") for (int nj = 0; nj < 2; ++nj) { \
    const int row_ = wn * 32 + (NH) * 128 + nj * 16 + lr; \
    const int sw_ = (row_ & 7) << 4; const int rb_ = row_ << 7; \
    _Pragma("unroll") for (int kk = 0; kk < 2; ++kk) \
      bf[NH][nj][kk] = *(const s16x8*)(pb + rb_ + (((kk << 6) | (kg << 4)) ^ sw_)); } } while (0)

#define MM(MH, NH) do { _Pragma("unroll") for (int kk = 0; kk < 2; ++kk) \
    _Pragma("unroll") for (int mi = 0; mi < 4; ++mi) \
    _Pragma("unroll") for (int nj = 0; nj < 2; ++nj) \
      acc[(MH) * 4 + mi][(NH) * 2 + nj] = __builtin_amdgcn_mfma_f32_16x16x32_bf16( \
        af[mi][kk], bf[NH][nj][kk], acc[(MH) * 4 + mi][(NH) * 2 + nj], 0, 0, 0); } while (0)

#define PH_SYNC do { __builtin_amdgcn_s_barrier(); \
    asm volatile("s_waitcnt lgkmcnt(0)"); \
    __builtin_amdgcn_sched_barrier(0); } while (0)

// bijective XCD permutation over ntiles (m204); ntiles % 8 == 0 in all our calls
__device__ __forceinline__ int perm8(int orig, int ntiles) {
  const int q = ntiles >> 3, r8 = ntiles & 7;
  const int xcd = orig & 7, pos = orig >> 3;
  return (xcd < r8 ? xcd * (q + 1) : r8 * (q + 1) + (xcd - r8) * q) + pos;
}

// Epilogue MODE: 1 = +bias; 2 = relu(+bias); 3 = exp(scale*acc) [scores];
//               4 = acc * linv[z*M+row] [PV]; 5 = +bias, route col>>10 to three
//               [*,1024] outputs spaced 16777216 elems (fused QKV).
template<int MODE>
__global__ __launch_bounds__(512, 2)
void gemm256p(const u16* __restrict__ A, const u16* __restrict__ BT,
              u16* __restrict__ C,
              const float* __restrict__ bias0, const float* __restrict__ bias1,
              const float* __restrict__ bias2, const float* __restrict__ linv,
              int M, int N, int K, int NBZ,
              long long sA, long long sB, long long sC, float scale) {
  __shared__ u16 SA[2][16384];
  __shared__ u16 SB[2][16384];

  const int tn = N >> 8;
  const int tilesPerZ = (M >> 8) * tn;
  const int ntiles = NBZ * tilesPerZ;
  const int NT = K >> 6;
  const long long ldb = (long long)K * 2;
  const int G = gridDim.x;

  const int tid = threadIdx.x;
  const int lane = tid & 63, wid = tid >> 6;
  const int lr = lane & 15, kg = lane >> 4;
  const int wm = wid >> 2, wn = wid & 3;

  // tile descriptor: cur and nxt
  const char *curA, *curB, *nxtA, *nxtB;
  long long curBm, curBn, nxtBm, nxtBn;
  int curZ, nxtZ;
  auto mk = [&](int tl, const char*& ag, const char*& bg,
                long long& bm, long long& bn, int& z) {
    z = tl / tilesPerZ;
    const int rm = tl - z * tilesPerZ;
    bm = (long long)(rm / tn) << 8;
    bn = (long long)(rm - (rm / tn) * tn) << 8;
    ag = (const char*)(A + (long long)z * sA);
    bg = (const char*)(BT + (long long)z * sB);
  };

  int jt = blockIdx.x;
  mk(perm8(jt, ntiles), curA, curB, curBm, curBn, curZ);
  bool hasNext = (jt + G) < ntiles;
  if (hasNext) mk(perm8(jt + G, ntiles), nxtA, nxtB, nxtBm, nxtBn, nxtZ);
  else { nxtA = curA; nxtB = curB; nxtBm = curBm; nxtBn = curBn; nxtZ = curZ; }

  f32x4 acc[8][4] = {};
  s16x8 af[4][2];
  s16x8 bf[2][2][2];

  // prologue: vt0 fully + vt1 first halves (NT >= 16 so both in cur)
  stage_half(curA, ldb, curBm, 0, 0, SA[0], tid);
  stage_half(curB, ldb, curBn, 0, 0, SB[0], tid);
  stage_half(curA, ldb, curBm, 0, 1, SA[0], tid);
  stage_half(curB, ldb, curBn, 0, 1, SB[0], tid);
  stage_half(curA, ldb, curBm, 1, 0, SA[1], tid);
  stage_half(curB, ldb, curBn, 1, 0, SB[1], tid);
  asm volatile("s_waitcnt vmcnt(4)");
  __builtin_amdgcn_s_barrier();

  int vt = 0;
  for (;;) {
    for (int T = 0; T < NT; ++T, ++vt) {
      const int c = vt & 1, cn = c ^ 1;
      const char* pa = (const char*)SA[c];
      const char* pb = (const char*)SB[c];

      // stage targets (virtual K-tiles vt+1, vt+2 roll into next output tile)
      const bool in1 = (T + 1 < NT), in2 = (T + 2 < NT);
      const bool v1 = in1 || hasNext, v2 = in2 || hasNext;
      const char* a1 = in1 ? curA : nxtA;  const char* b1 = in1 ? curB : nxtB;
      const long long m1 = in1 ? curBm : nxtBm, n1 = in1 ? curBn : nxtBn;
      const int tk1 = in1 ? T + 1 : 0;
      const char* a2 = in2 ? curA : nxtA;  const char* b2 = in2 ? curB : nxtB;
      const long long m2 = in2 ? curBm : nxtBm, n2 = in2 ? curBn : nxtBn;
      const int tk2 = in2 ? T + 2 : T + 2 - NT;

      // ---- phase 0: quadrant (mh0, nh0); stage (vt+1).Ah1 -> buf cn
      RD_A(0); RD_B(0);
      if (v1) stage_half(a1, ldb, m1, tk1, 1, SA[cn], tid);
      PH_SYNC;
      __builtin_amdgcn_s_setprio(1); MM(0, 0); __builtin_amdgcn_s_setprio(0);
      __builtin_amdgcn_s_barrier();

      // ---- phase 1: (mh0, nh1); stage (vt+1).Bh1 -> buf cn
      RD_B(1);
      if (v1) stage_half(b1, ldb, n1, tk1, 1, SB[cn], tid);
      PH_SYNC;
      __builtin_amdgcn_s_setprio(1); MM(0, 1); __builtin_amdgcn_s_setprio(0);
      __builtin_amdgcn_s_barrier();

      // ---- phase 2: (mh1, nh0); stage (vt+2).Ah0 -> buf c
      RD_A(1);
      if (v2) stage_half(a2, ldb, m2, tk2, 0, SA[c], tid);
      PH_SYNC;
      __builtin_amdgcn_s_setprio(1); MM(1, 0); __builtin_amdgcn_s_setprio(0);
      __builtin_amdgcn_s_barrier();

      // ---- phase 3: (mh1, nh1); stage (vt+2).Bh0 -> buf c; counted boundary wait
      if (v2) stage_half(b2, ldb, n2, tk2, 0, SB[c], tid);
      PH_SYNC;
      __builtin_amdgcn_s_setprio(1); MM(1, 1); __builtin_amdgcn_s_setprio(0);
      if (v2)      { asm volatile("s_waitcnt vmcnt(4)"); }
      else if (v1) { asm volatile("s_waitcnt vmcnt(0)"); }
      __builtin_amdgcn_s_barrier();
    }

    // ---- epilogue for cur; next tile's first loads already in flight
    {
      u16* Cb = C + (long long)curZ * sC;
      const long long zM = (long long)curZ * M;
#pragma unroll
      for (int nh = 0; nh < 2; ++nh)
#pragma unroll
        for (int nj = 0; nj < 2; ++nj) {
          const long long col = curBn + wn * 32 + nh * 128 + nj * 16 + lr;
          u16* outp = Cb;
          long long ccol = col, ldc = N;
          float bv = 0.f;
          if (MODE == 1 || MODE == 2) bv = bias0[col];
          if (MODE == 5) {
            const int sel = (int)(col >> 10);
            outp = C + (long long)sel * 16777216;
            ccol = col & 1023; ldc = 1024;
            bv = (sel == 0 ? bias0 : sel == 1 ? bias1 : bias2)[ccol];
          }
#pragma unroll
          for (int mh = 0; mh < 2; ++mh)
#pragma unroll
            for (int mi = 0; mi < 4; ++mi) {
              const long long row0 = curBm + wm * 64 + mh * 128 + mi * 16 + kg * 4;
#pragma unroll
              for (int r = 0; r < 4; ++r) {
                float v = acc[mh * 4 + mi][nh * 2 + nj][r];
                if (MODE == 1 || MODE == 2 || MODE == 5) v = v * scale + bv;
                if (MODE == 2) v = fmaxf(v, 0.f);
                if (MODE == 3) v = __expf(v * scale);
                if (MODE == 4) v = v * linv[zM + row0 + r];
                outp[(row0 + r) * ldc + ccol] = (u16)f2bf(v);
              }
            }
        }
    }

    jt += G;
    if (jt >= ntiles) break;
    // rotate descriptors; zero accumulators
    curA = nxtA; curB = nxtB; curBm = nxtBm; curBn = nxtBn; curZ = nxtZ;
    hasNext = (jt + G) < ntiles;
    if (hasNext) mk(perm8(jt + G, ntiles), nxtA, nxtB, nxtBm, nxtBn, nxtZ);
#pragma unroll
    for (int i = 0; i < 8; ++i)
#pragma unroll
      for (int j = 0; j < 4; ++j) acc[i][j] = (f32x4){0.f, 0.f, 0.f, 0.f};
  }
}

// ---------------------------------------------------------------- cast x -> bf16
__global__ __launch_bounds__(256) void cast_f32_bf16(const float* __restrict__ in,
                                                     u16* __restrict__ out) {
  long long i = (long long)blockIdx.x * 256 + threadIdx.x;
  f32x4 v = ((const f32x4*)in)[i];
  s16x4 o;
#pragma unroll
  for (int j = 0; j < 4; j++) o[j] = f2bf(v[j]);
  ((s16x4*)out)[i] = o;
}

// ------------------------------------------------- transpose fp32 [R,C] -> bf16 [C,R]
__global__ __launch_bounds__(256) void transpose_f32_bf16(const float* __restrict__ in,
                                                          u16* __restrict__ out,
                                                          int R, int C) {
  __shared__ float tile[32][33];
  const int tx = threadIdx.x, ty = threadIdx.y;
  const int r0 = blockIdx.y * 32, c0 = blockIdx.x * 32;
#pragma unroll
  for (int i = 0; i < 32; i += 8)
    tile[ty + i][tx] = in[(long long)(r0 + ty + i) * C + (c0 + tx)];
  __syncthreads();
#pragma unroll
  for (int i = 0; i < 32; i += 8)
    out[(long long)(c0 + ty + i) * R + (r0 + tx)] = (u16)f2bf(tile[tx][ty + i]);
}

// ------------------------------------------------- transpose bf16 [R,C] -> bf16 [C,R] (batched)
__global__ __launch_bounds__(256) void transpose_bf16_bf16(const u16* __restrict__ in,
                                                           u16* __restrict__ out,
                                                           int R, int C,
                                                           long long isb, long long osb) {
  __shared__ u16 tile[32][33];
  in  += (long long)blockIdx.z * isb;
  out += (long long)blockIdx.z * osb;
  const int tx = threadIdx.x, ty = threadIdx.y;
  const int r0 = blockIdx.y * 32, c0 = blockIdx.x * 32;
#pragma unroll
  for (int i = 0; i < 32; i += 8)
    tile[ty + i][tx] = in[(long long)(r0 + ty + i) * C + (c0 + tx)];
  __syncthreads();
#pragma unroll
  for (int i = 0; i < 32; i += 8)
    out[(long long)(c0 + ty + i) * R + (r0 + tx)] = tile[tx][ty + i];
}

// ---------------------------------------------------------------- row sum -> 1/l (2048 cols)
__global__ __launch_bounds__(256) void rowinv2048(const u16* __restrict__ P,
                                                  float* __restrict__ linv) {
  const long long row = blockIdx.x;
  const u16* p = P + row * 2048;
  const int t = threadIdx.x;
  s16x8 raw = *(const s16x8*)&p[t * 8];
  float s = 0.f;
#pragma unroll
  for (int j = 0; j < 8; j++) s += bf2f(raw[j]);
#pragma unroll
  for (int off = 32; off > 0; off >>= 1) s += __shfl_xor(s, off);
  __shared__ float red[4];
  if ((t & 63) == 0) red[t >> 6] = s;
  __syncthreads();
  if (t == 0) {
    s = (red[0] + red[1]) + (red[2] + red[3]);
    linv[row] = 1.0f / s;
  }
}

// ---------------------------------------------------------------- LN(x_f32 + a_bf16) -> bf16
__global__ __launch_bounds__(256) void ln_add_f32bf16(const float* __restrict__ x,
                                                      const u16* __restrict__ a,
                                                      const float* __restrict__ g,
                                                      const float* __restrict__ be,
                                                      u16* __restrict__ out) {
  const long long row = blockIdx.x;
  const int t = threadIdx.x;
  f32x4 xv = ((const f32x4*)(x + row * 1024))[t];
  s16x4 av = ((const s16x4*)(a + row * 1024))[t];
  float v[4]; float sum = 0.f, ss = 0.f;
#pragma unroll
  for (int j = 0; j < 4; j++) { v[j] = xv[j] + bf2f(av[j]); sum += v[j]; ss += v[j] * v[j]; }
#pragma unroll
  for (int off = 32; off > 0; off >>= 1) { sum += __shfl_xor(sum, off); ss += __shfl_xor(ss, off); }
  __shared__ float red[8];
  if ((t & 63) == 0) { red[t >> 6] = sum; red[4 + (t >> 6)] = ss; }
  __syncthreads();
  sum = (red[0] + red[1]) + (red[2] + red[3]);
  ss  = (red[4] + red[5]) + (red[6] + red[7]);
  const float mu   = sum * (1.f / 1024.f);
  const float var  = ss * (1.f / 1024.f) - mu * mu;
  const float rstd = rsqrtf(var + 1e-5f);
  s16x4 o;
#pragma unroll
  for (int j = 0; j < 4; j++) {
    const int c = t * 4 + j;
    o[j] = f2bf((v[j] - mu) * rstd * g[c] + be[c]);
  }
  *(s16x4*)&out[row * 1024 + t * 4] = o;
}

// ---------------------------------------------------------------- LN(h_bf16 + f_bf16) -> fp32
__global__ __launch_bounds__(256) void ln_add_bf16bf16(const u16* __restrict__ h,
                                                       const u16* __restrict__ f,
                                                       const float* __restrict__ g,
                                                       const float* __restrict__ be,
                                                       float* __restrict__ out) {
  const long long row = blockIdx.x;
  const int t = threadIdx.x;
  s16x4 hv = ((const s16x4*)(h + row * 1024))[t];
  s16x4 fv = ((const s16x4*)(f + row * 1024))[t];
  float v[4]; float sum = 0.f, ss = 0.f;
#pragma unroll
  for (int j = 0; j < 4; j++) { v[j] = bf2f(hv[j]) + bf2f(fv[j]); sum += v[j]; ss += v[j] * v[j]; }
#pragma unroll
  for (int off = 32; off > 0; off >>= 1) { sum += __shfl_xor(sum, off); ss += __shfl_xor(ss, off); }
  __shared__ float red[8];
  if ((t & 63) == 0) { red[t >> 6] = sum; red[4 + (t >> 6)] = ss; }
  __syncthreads();
  sum = (red[0] + red[1]) + (red[2] + red[3]);
  ss  = (red[4] + red[5]) + (red[6] + red[7]);
  const float mu   = sum * (1.f / 1024.f);
  const float var  = ss * (1.f / 1024.f) - mu * mu;
  const float rstd = rsqrtf(var + 1e-5f);
  f32x4 o;
#pragma unroll
  for (int j = 0; j < 4; j++) {
    const int c = t * 4 + j;
    o[j] = (v[j] - mu) * rstd * g[c] + be[c];
  }
  ((f32x4*)(out + row * 1024))[t] = o;
}

// ---------------------------------------------------------------- launcher
extern "C" void kernel_launch(void* const* d_in, const int* in_sizes, int n_in,
                              void* d_out, int out_size, void* d_ws, size_t ws_size,
                              hipStream_t stream) {
  const float* x   = (const float*)d_in[0];
  const float* Wq  = (const float*)d_in[1];
  const float* bq  = (const float*)d_in[2];
  const float* Wk  = (const float*)d_in[3];
  const float* bk  = (const float*)d_in[4];
  const float* Wv  = (const float*)d_in[5];
  const float* bv  = (const float*)d_in[6];
  const float* Wo  = (const float*)d_in[7];
  const float* bo  = (const float*)d_in[8];
  const float* g1  = (const float*)d_in[9];
  const float* b1  = (const float*)d_in[10];
  const float* g2  = (const float*)d_in[11];
  const float* b2  = (const float*)d_in[12];
  const float* W1  = (const float*)d_in[13];
  const float* bf1 = (const float*)d_in[14];
  const float* W2  = (const float*)d_in[15];
  const float* bf2 = (const float*)d_in[16];
  float* out = (float*)d_out;

  // workspace layout (bytes), ~248 MiB, with aliasing.
  // weights 0..25165824 (WQT/WKT/WVT contiguous = fused [3072,1024]); XB 32MiB;
  // Q 32MiB; K 32MiB; V 32MiB; VT 32MiB; S 64MiB.
  // Aliases: AO->XB, AO2->Q, H->K, HID->[V..S end] (128MiB), FFN->XB, linv->Q start.
  char* ws = (char*)d_ws;
  u16* wsWQT = (u16*)(ws + 0);           // fused QKV weight base [3072,1024]
  u16* wsWKT = (u16*)(ws + 2097152);
  u16* wsWVT = (u16*)(ws + 4194304);
  u16* wsWOT = (u16*)(ws + 6291456);
  u16* wsW1T = (u16*)(ws + 8388608);     // [4096,1024] bf16, 8 MiB
  u16* wsW2T = (u16*)(ws + 16777216);    // [1024,4096] bf16, 8 MiB
  u16* wsXB  = (u16*)(ws + 25165824);    // [16384,1024] bf16 tokens, 32 MiB
  u16* wsQ   = (u16*)(ws + 58720256);    // Q/K/V contiguous (QKV epilogue routing)
  u16* wsK   = (u16*)(ws + 92274688);
  u16* wsV   = (u16*)(ws + 125829120);
  u16* wsVT  = (u16*)(ws + 159383552);   // [8][1024,2048] bf16, 32 MiB
  u16* wsS   = (u16*)(ws + 192937984);   // [8][2048,2048] bf16 P~ = exp(s), 64 MiB
  u16* wsAO  = wsXB;
  u16* wsAO2 = wsQ;
  u16* wsH   = wsK;
  u16* wsHID = wsV;                      // [16384,4096] bf16, 128 MiB (covers V,VT,S)
  u16* wsFFN = wsXB;
  float* wsLINV = (float*)wsQ;           // 64 KiB; Q dead during PV, AO2 written after

  const dim3 tb(32, 8, 1);
  const float inv_sqrt_e = 0.03125f;   // 1/sqrt(1024)
  const float* nf = nullptr;

  // 1) cast x -> bf16
  cast_f32_bf16<<<16384, 256, 0, stream>>>(x, wsXB);

  // 2) weights -> bf16 transposed [N,K]  (Wq/Wk/Wv land contiguous)
  transpose_f32_bf16<<<dim3(32, 32, 1),  tb, 0, stream>>>(Wq, wsWQT, 1024, 1024);
  transpose_f32_bf16<<<dim3(32, 32, 1),  tb, 0, stream>>>(Wk, wsWKT, 1024, 1024);
  transpose_f32_bf16<<<dim3(32, 32, 1),  tb, 0, stream>>>(Wv, wsWVT, 1024, 1024);
  transpose_f32_bf16<<<dim3(32, 32, 1),  tb, 0, stream>>>(Wo, wsWOT, 1024, 1024);
  transpose_f32_bf16<<<dim3(128, 32, 1), tb, 0, stream>>>(W1, wsW1T, 1024, 4096);
  transpose_f32_bf16<<<dim3(32, 128, 1), tb, 0, stream>>>(W2, wsW2T, 4096, 1024);

  // 3) fused QKV: [16384,1024] x [3072,1024]^T (768 tiles, 3/block)
  gemm256p<5><<<256, 512, 0, stream>>>(wsXB, wsWQT, wsQ, bq, bk, bv, nf,
                                       16384, 3072, 1024, 1, 0, 0, 0, 1.f);

  // 4) V -> V^T per batch: [2048,1024] -> [1024,2048]
  transpose_bf16_bf16<<<dim3(32, 64, 8), tb, 0, stream>>>(wsV, wsVT, 2048, 1024, 2048LL * 1024, 1024LL * 2048);

  // 5) P~ = exp(Q K^T / 32) : batched (512 tiles, 2/block)
  gemm256p<3><<<256, 512, 0, stream>>>(wsQ, wsK, wsS, nf, nf, nf, nf,
                                       2048, 2048, 1024, 8,
                                       2048LL * 1024, 2048LL * 1024, 2048LL * 2048, inv_sqrt_e);
  // 6) linv[row] = 1 / rowsum(P~)
  rowinv2048<<<16384, 256, 0, stream>>>(wsS, wsLINV);

  // 7) attn_out = (P~ V) * linv : batched (256 tiles)
  gemm256p<4><<<256, 512, 0, stream>>>(wsS, wsVT, wsAO, nf, nf, nf, wsLINV,
                                       2048, 1024, 2048, 8,
                                       2048LL * 2048, 1024LL * 2048, 2048LL * 1024, 1.f);
  // 8) out-proj (256 tiles)
  gemm256p<1><<<256, 512, 0, stream>>>(wsAO, wsWOT, wsAO2, bo, nf, nf, nf,
                                       16384, 1024, 1024, 1, 0, 0, 0, 1.f);

  // 9) h = LN(x + AO2)
  ln_add_f32bf16<<<16384, 256, 0, stream>>>(x, wsAO2, g1, b1, wsH);

  // 10) HID = relu(h W1 + bf1) : (1024 tiles, 4/block)
  gemm256p<2><<<256, 512, 0, stream>>>(wsH, wsW1T, wsHID, bf1, nf, nf, nf,
                                       16384, 4096, 1024, 1, 0, 0, 0, 1.f);

  // 11) FFN = HID W2 + bf2 : (256 tiles)
  gemm256p<1><<<256, 512, 0, stream>>>(wsHID, wsW2T, wsFFN, bf2, nf, nf, nf,
                                       16384, 1024, 4096, 1, 0, 0, 0, 1.f);

  // 12) out = LN(h + FFN), fp32
  ln_add_bf16bf16<<<16384, 256, 0, stream>>>(wsH, wsFFN, g2, b2, out);

  (void)in_sizes; (void)n_in; (void)out_size; (void)ws_size;
}

// Round 7
// 658.743 us; speedup vs baseline: 1.1369x; 1.1369x over previous
//
#include <hip/hip_runtime.h>

// BERT encoder block fwd. R7 = R6 with compile fix: LDS double-buffer bases are
// computed inline (macros), not stored in a pointer array (addrspacecast static
// initializer is rejected on gfx950).
// R6 change under test: LDS-staged coalesced epilogue — acc -> LDS (XOR-swizzled,
// conflict-free) -> 16B/lane coalesced stores. Kills partial-line RMW fetch.
// Keeps R5's linv batch fix (linv[z*M+row]).

typedef __attribute__((ext_vector_type(4))) float  f32x4;
typedef __attribute__((ext_vector_type(8))) short  s16x8;
typedef __attribute__((ext_vector_type(4))) short  s16x4;
typedef unsigned short u16;
typedef unsigned int   u32;

__device__ __forceinline__ float bf2f(short s) {
  u32 u = ((u32)(u16)s) << 16;
  float f; __builtin_memcpy(&f, &u, 4); return f;
}
__device__ __forceinline__ short f2bf(float f) {
  u32 u; __builtin_memcpy(&u, &f, 4);
  u32 r = (u + 0x7fffu + ((u >> 16) & 1u)) >> 16;   // RNE
  return (short)(u16)r;
}

// async global->LDS, 16B/lane; LDS dest must be wave-uniform base + lane*16
__device__ __forceinline__ void gload16(const void* g, void* l) {
  __builtin_amdgcn_global_load_lds(
      (const __attribute__((address_space(1))) u32*)g,
      (__attribute__((address_space(3))) u32*)l, 16, 0, 0);
}

// stage one 128-row half of a 256x64 bf16 tile (2 gload16/thread, 512 threads)
__device__ __forceinline__ void stage_half(const char* gop, long long ldb,
                                           long long rowbase, int tt, int h,
                                           u16* ldsop, int tid) {
#pragma unroll
  for (int l = 0; l < 2; ++l) {
    const int o   = (l * 512 + tid) * 16;          // linear byte offset in half (16 KiB)
    const int rih = o >> 7;                        // row in half 0..127
    const int scb = (o & 127) ^ ((rih & 7) << 4);  // inverse-swizzled source col-byte
    gload16(gop + (rowbase + h * 128 + rih) * ldb + (long long)tt * 128 + scb,
            (char*)ldsop + h * 16384 + o);
  }
}

#define SABUF(c) (SMEM + (c) * 16384)
#define SBBUF(c) (SMEM + 32768 + (c) * 16384)

#define RD_A(MH) do { _Pragma("unroll") for (int mi = 0; mi < 4; ++mi) { \
    const int row_ = wm * 64 + (MH) * 128 + mi * 16 + lr; \
    const int sw_ = (row_ & 7) << 4; const int rb_ = row_ << 7; \
    _Pragma("unroll") for (int kk = 0; kk < 2; ++kk) \
      af[mi][kk] = *(const s16x8*)(pa + rb_ + (((kk << 6) | (kg << 4)) ^ sw_)); } } while (0)

#define RD_B(NH) do { _Pragma("unroll") for (int nj = 0; nj < 2; ++nj) { \
    const int row_ = wn * 32 + (NH) * 128 + nj * 16 + lr; \
    const int sw_ = (row_ & 7) << 4; const int rb_ = row_ << 7; \
    _Pragma("unroll") for (int kk = 0; kk < 2; ++kk) \
      bf[NH][nj][kk] = *(const s16x8*)(pb + rb_ + (((kk << 6) | (kg << 4)) ^ sw_)); } } while (0)

#define MM(MH, NH) do { _Pragma("unroll") for (int kk = 0; kk < 2; ++kk) \
    _Pragma("unroll") for (int mi = 0; mi < 4; ++mi) \
    _Pragma("unroll") for (int nj = 0; nj < 2; ++nj) \
      acc[(MH) * 4 + mi][(NH) * 2 + nj] = __builtin_amdgcn_mfma_f32_16x16x32_bf16( \
        af[mi][kk], bf[NH][nj][kk], acc[(MH) * 4 + mi][(NH) * 2 + nj], 0, 0, 0); } while (0)

#define PH_SYNC do { __builtin_amdgcn_s_barrier(); \
    asm volatile("s_waitcnt lgkmcnt(0)"); \
    __builtin_amdgcn_sched_barrier(0); } while (0)

// Epilogue MODE: 1 = +bias; 2 = relu(+bias); 3 = exp(scale*acc) [scores];
//               4 = acc * linv[z*M+row] [PV]; 5 = +bias, route col>>10 to three
//               [*,1024] outputs spaced 16777216 elems (fused QKV; 256-col tiles
//               never straddle a 1024 boundary, so routing is tile-uniform).
template<int MODE>
__global__ __launch_bounds__(512, 2)
void gemm256(const u16* __restrict__ A, const u16* __restrict__ BT,
             u16* __restrict__ C,
             const float* __restrict__ bias0, const float* __restrict__ bias1,
             const float* __restrict__ bias2, const float* __restrict__ linv,
             int M, int N, int K, float scale,
             long long sA, long long sB, long long sC) {
  __shared__ u16 SMEM[65536];   // K-loop: SA dbuf | SB dbuf (4 x 16K u16); epilogue: [256][256]

  // T1: bijective XCD swizzle over flattened 3D grid (m204)
  const int gx = gridDim.x, gy = gridDim.y;
  const int nwg = gx * gy * gridDim.z;
  const int orig = (blockIdx.z * gy + blockIdx.y) * gx + blockIdx.x;
  const int q = nwg >> 3, r8 = nwg & 7;
  const int xcd = orig & 7, pos = orig >> 3;
  const int wg = (xcd < r8 ? xcd * (q + 1) : r8 * (q + 1) + (xcd - r8) * q) + pos;
  const int bz = wg / (gx * gy);
  const int rem = wg % (gx * gy);
  const long long bm = (long long)(rem / gx) * 256;
  const long long bn = (long long)(rem % gx) * 256;

  const char* Ag = (const char*)(A + (long long)bz * sA);
  const char* Bg = (const char*)(BT + (long long)bz * sB);
  u16* Cb = C + (long long)bz * sC;
  const long long ldb = (long long)K * 2;

  const int tid = threadIdx.x;
  const int lane = tid & 63, wid = tid >> 6;
  const int lr = lane & 15, kg = lane >> 4;
  const int wm = wid >> 2, wn = wid & 3;
  const int NT = K >> 6;

  f32x4 acc[8][4] = {};
  s16x8 af[4][2];
  s16x8 bf[2][2][2];

  // prologue: T0 fully + T1 first halves; wait T0 (4 loads may stay in flight)
  stage_half(Ag, ldb, bm, 0, 0, SABUF(0), tid);
  stage_half(Bg, ldb, bn, 0, 0, SBBUF(0), tid);
  stage_half(Ag, ldb, bm, 0, 1, SABUF(0), tid);
  stage_half(Bg, ldb, bn, 0, 1, SBBUF(0), tid);
  stage_half(Ag, ldb, bm, 1, 0, SABUF(1), tid);
  stage_half(Bg, ldb, bn, 1, 0, SBBUF(1), tid);
  asm volatile("s_waitcnt vmcnt(4)");
  __builtin_amdgcn_s_barrier();

  for (int T = 0; T < NT; ++T) {
    const int c = T & 1, cn = c ^ 1;
    const char* pa = (const char*)SABUF(c);
    const char* pb = (const char*)SBBUF(c);

    // ---- phase 0: quadrant (mh0, nh0); stage (T+1).Ah1
    RD_A(0); RD_B(0);
    if (T + 1 < NT) stage_half(Ag, ldb, bm, T + 1, 1, SABUF(cn), tid);
    PH_SYNC;
    __builtin_amdgcn_s_setprio(1); MM(0, 0); __builtin_amdgcn_s_setprio(0);
    __builtin_amdgcn_s_barrier();

    // ---- phase 1: (mh0, nh1); stage (T+1).Bh1
    RD_B(1);
    if (T + 1 < NT) stage_half(Bg, ldb, bn, T + 1, 1, SBBUF(cn), tid);
    PH_SYNC;
    __builtin_amdgcn_s_setprio(1); MM(0, 1); __builtin_amdgcn_s_setprio(0);
    __builtin_amdgcn_s_barrier();

    // ---- phase 2: (mh1, nh0); stage (T+2).Ah0
    RD_A(1);
    if (T + 2 < NT) stage_half(Ag, ldb, bm, T + 2, 0, SABUF(c), tid);
    PH_SYNC;
    __builtin_amdgcn_s_setprio(1); MM(1, 0); __builtin_amdgcn_s_setprio(0);
    __builtin_amdgcn_s_barrier();

    // ---- phase 3: (mh1, nh1); stage (T+2).Bh0; counted boundary wait
    if (T + 2 < NT) stage_half(Bg, ldb, bn, T + 2, 0, SBBUF(c), tid);
    PH_SYNC;
    __builtin_amdgcn_s_setprio(1); MM(1, 1); __builtin_amdgcn_s_setprio(0);
    if (T + 2 < NT)      { asm volatile("s_waitcnt vmcnt(4)"); }
    else if (T + 1 < NT) { asm volatile("s_waitcnt vmcnt(0)"); }
    __builtin_amdgcn_s_barrier();
  }

  // ---- epilogue: acc -> LDS (swizzled conflict-free) -> coalesced 16B stores.
  // Write swizzle: element col' = col ^ (kg<<4)  (kg = row bits 2..3) spreads the
  // four kg row-groups across disjoint bank octets (2 lanes/bank = free).
  const long long zM = (long long)bz * M;
  u16* obase; long long ldc, bnl;
  const float* bptr = bias0;
  if (MODE == 5) {
    const int sel = (int)(bn >> 10);
    obase = C + (long long)sel * 16777216;
    ldc = 1024; bnl = bn & 1023;
    bptr = (sel == 0 ? bias0 : sel == 1 ? bias1 : bias2);
  } else { obase = Cb; ldc = N; bnl = bn; }

#pragma unroll
  for (int nh = 0; nh < 2; ++nh)
#pragma unroll
    for (int nj = 0; nj < 2; ++nj) {
      const int col = wn * 32 + nh * 128 + nj * 16 + lr;     // local col 0..255
      float bv = 0.f;
      if (MODE == 1 || MODE == 2 || MODE == 5) bv = bptr[bnl + col];
#pragma unroll
      for (int mh = 0; mh < 2; ++mh)
#pragma unroll
        for (int mi = 0; mi < 4; ++mi) {
          const int row0 = wm * 64 + mh * 128 + mi * 16 + kg * 4;  // local row
#pragma unroll
          for (int r = 0; r < 4; ++r) {
            float v = acc[mh * 4 + mi][nh * 2 + nj][r];
            if (MODE == 1 || MODE == 2 || MODE == 5) v = v * scale + bv;
            if (MODE == 2) v = fmaxf(v, 0.f);
            if (MODE == 3) v = __expf(v * scale);
            if (MODE == 4) v = v * linv[zM + bm + row0 + r];
            SMEM[(row0 + r) * 256 + (col ^ (kg << 4))] = (u16)f2bf(v);
          }
        }
    }
  __syncthreads();
#pragma unroll
  for (int i = 0; i < 16; ++i) {
    const int o   = (i * 512 + tid) * 16;          // byte offset in 128KiB tile
    const int row = o >> 9;                        // local row (512 B/row)
    const int wb  = o & 511;                       // byte-in-row = local col*2
    const int gs  = (wb >> 4) ^ (((row >> 2) & 3) << 1);  // inverse granule swizzle
    s16x8 d = *(const s16x8*)((const char*)SMEM + row * 512 + (gs << 4));
    *(s16x8*)((char*)obase + (((long long)bm + row) * ldc + bnl) * 2 + wb) = d;
  }
}

// ---------------------------------------------------------------- cast x -> bf16
__global__ __launch_bounds__(256) void cast_f32_bf16(const float* __restrict__ in,
                                                     u16* __restrict__ out) {
  long long i = (long long)blockIdx.x * 256 + threadIdx.x;
  f32x4 v = ((const f32x4*)in)[i];
  s16x4 o;
#pragma unroll
  for (int j = 0; j < 4; j++) o[j] = f2bf(v[j]);
  ((s16x4*)out)[i] = o;
}

// ------------------------------------------------- transpose fp32 [R,C] -> bf16 [C,R]
__global__ __launch_bounds__(256) void transpose_f32_bf16(const float* __restrict__ in,
                                                          u16* __restrict__ out,
                                                          int R, int C) {
  __shared__ float tile[32][33];
  const int tx = threadIdx.x, ty = threadIdx.y;
  const int r0 = blockIdx.y * 32, c0 = blockIdx.x * 32;
#pragma unroll
  for (int i = 0; i < 32; i += 8)
    tile[ty + i][tx] = in[(long long)(r0 + ty + i) * C + (c0 + tx)];
  __syncthreads();
#pragma unroll
  for (int i = 0; i < 32; i += 8)
    out[(long long)(c0 + ty + i) * R + (r0 + tx)] = (u16)f2bf(tile[tx][ty + i]);
}

// ------------------------------------------------- transpose bf16 [R,C] -> bf16 [C,R] (batched)
__global__ __launch_bounds__(256) void transpose_bf16_bf16(const u16* __restrict__ in,
                                                           u16* __restrict__ out,
                                                           int R, int C,
                                                           long long isb, long long osb) {
  __shared__ u16 tile[32][33];
  in  += (long long)blockIdx.z * isb;
  out += (long long)blockIdx.z * osb;
  const int tx = threadIdx.x, ty = threadIdx.y;
  const int r0 = blockIdx.y * 32, c0 = blockIdx.x * 32;
#pragma unroll
  for (int i = 0; i < 32; i += 8)
    tile[ty + i][tx] = in[(long long)(r0 + ty + i) * C + (c0 + tx)];
  __syncthreads();
#pragma unroll
  for (int i = 0; i < 32; i += 8)
    out[(long long)(c0 + ty + i) * R + (r0 + tx)] = tile[tx][ty + i];
}

// ---------------------------------------------------------------- row sum -> 1/l (2048 cols)
__global__ __launch_bounds__(256) void rowinv2048(const u16* __restrict__ P,
                                                  float* __restrict__ linv) {
  const long long row = blockIdx.x;
  const u16* p = P + row * 2048;
  const int t = threadIdx.x;
  s16x8 raw = *(const s16x8*)&p[t * 8];
  float s = 0.f;
#pragma unroll
  for (int j = 0; j < 8; j++) s += bf2f(raw[j]);
#pragma unroll
  for (int off = 32; off > 0; off >>= 1) s += __shfl_xor(s, off);
  __shared__ float red[4];
  if ((t & 63) == 0) red[t >> 6] = s;
  __syncthreads();
  if (t == 0) {
    s = (red[0] + red[1]) + (red[2] + red[3]);
    linv[row] = 1.0f / s;
  }
}

// ---------------------------------------------------------------- LN(x_f32 + a_bf16) -> bf16
__global__ __launch_bounds__(256) void ln_add_f32bf16(const float* __restrict__ x,
                                                      const u16* __restrict__ a,
                                                      const float* __restrict__ g,
                                                      const float* __restrict__ be,
                                                      u16* __restrict__ out) {
  const long long row = blockIdx.x;
  const int t = threadIdx.x;
  f32x4 xv = ((const f32x4*)(x + row * 1024))[t];
  s16x4 av = ((const s16x4*)(a + row * 1024))[t];
  float v[4]; float sum = 0.f, ss = 0.f;
#pragma unroll
  for (int j = 0; j < 4; j++) { v[j] = xv[j] + bf2f(av[j]); sum += v[j]; ss += v[j] * v[j]; }
#pragma unroll
  for (int off = 32; off > 0; off >>= 1) { sum += __shfl_xor(sum, off); ss += __shfl_xor(ss, off); }
  __shared__ float red[8];
  if ((t & 63) == 0) { red[t >> 6] = sum; red[4 + (t >> 6)] = ss; }
  __syncthreads();
  sum = (red[0] + red[1]) + (red[2] + red[3]);
  ss  = (red[4] + red[5]) + (red[6] + red[7]);
  const float mu   = sum * (1.f / 1024.f);
  const float var  = ss * (1.f / 1024.f) - mu * mu;
  const float rstd = rsqrtf(var + 1e-5f);
  s16x4 o;
#pragma unroll
  for (int j = 0; j < 4; j++) {
    const int c = t * 4 + j;
    o[j] = f2bf((v[j] - mu) * rstd * g[c] + be[c]);
  }
  *(s16x4*)&out[row * 1024 + t * 4] = o;
}

// ---------------------------------------------------------------- LN(h_bf16 + f_bf16) -> fp32
__global__ __launch_bounds__(256) void ln_add_bf16bf16(const u16* __restrict__ h,
                                                       const u16* __restrict__ f,
                                                       const float* __restrict__ g,
                                                       const float* __restrict__ be,
                                                       float* __restrict__ out) {
  const long long row = blockIdx.x;
  const int t = threadIdx.x;
  s16x4 hv = ((const s16x4*)(h + row * 1024))[t];
  s16x4 fv = ((const s16x4*)(f + row * 1024))[t];
  float v[4]; float sum = 0.f, ss = 0.f;
#pragma unroll
  for (int j = 0; j < 4; j++) { v[j] = bf2f(hv[j]) + bf2f(fv[j]); sum += v[j]; ss += v[j] * v[j]; }
#pragma unroll
  for (int off = 32; off > 0; off >>= 1) { sum += __shfl_xor(sum, off); ss += __shfl_xor(ss, off); }
  __shared__ float red[8];
  if ((t & 63) == 0) { red[t >> 6] = sum; red[4 + (t >> 6)] = ss; }
  __syncthreads();
  sum = (red[0] + red[1]) + (red[2] + red[3]);
  ss  = (red[4] + red[5]) + (red[6] + red[7]);
  const float mu   = sum * (1.f / 1024.f);
  const float var  = ss * (1.f / 1024.f) - mu * mu;
  const float rstd = rsqrtf(var + 1e-5f);
  f32x4 o;
#pragma unroll
  for (int j = 0; j < 4; j++) {
    const int c = t * 4 + j;
    o[j] = (v[j] - mu) * rstd * g[c] + be[c];
  }
  ((f32x4*)(out + row * 1024))[t] = o;
}

// ---------------------------------------------------------------- launcher
extern "C" void kernel_launch(void* const* d_in, const int* in_sizes, int n_in,
                              void* d_out, int out_size, void* d_ws, size_t ws_size,
                              hipStream_t stream) {
  const float* x   = (const float*)d_in[0];
  const float* Wq  = (const float*)d_in[1];
  const float* bq  = (const float*)d_in[2];
  const float* Wk  = (const float*)d_in[3];
  const float* bk  = (const float*)d_in[4];
  const float* Wv  = (const float*)d_in[5];
  const float* bv  = (const float*)d_in[6];
  const float* Wo  = (const float*)d_in[7];
  const float* bo  = (const float*)d_in[8];
  const float* g1  = (const float*)d_in[9];
  const float* b1  = (const float*)d_in[10];
  const float* g2  = (const float*)d_in[11];
  const float* b2  = (const float*)d_in[12];
  const float* W1  = (const float*)d_in[13];
  const float* bf1 = (const float*)d_in[14];
  const float* W2  = (const float*)d_in[15];
  const float* bf2 = (const float*)d_in[16];
  float* out = (float*)d_out;

  // workspace layout (bytes), ~248 MiB, with aliasing.
  // weights 0..25165824 (WQT/WKT/WVT contiguous = fused [3072,1024]); XB 32MiB;
  // Q 32MiB; K 32MiB; V 32MiB; VT 32MiB; S 64MiB.
  // Aliases: AO->XB, AO2->Q, H->K, HID->[V..S end] (128MiB), FFN->XB, linv->Q start.
  char* ws = (char*)d_ws;
  u16* wsWQT = (u16*)(ws + 0);           // fused QKV weight base [3072,1024]
  u16* wsWKT = (u16*)(ws + 2097152);
  u16* wsWVT = (u16*)(ws + 4194304);
  u16* wsWOT = (u16*)(ws + 6291456);
  u16* wsW1T = (u16*)(ws + 8388608);     // [4096,1024] bf16, 8 MiB
  u16* wsW2T = (u16*)(ws + 16777216);    // [1024,4096] bf16, 8 MiB
  u16* wsXB  = (u16*)(ws + 25165824);    // [16384,1024] bf16 tokens, 32 MiB
  u16* wsQ   = (u16*)(ws + 58720256);    // Q/K/V contiguous (QKV epilogue routing)
  u16* wsK   = (u16*)(ws + 92274688);
  u16* wsV   = (u16*)(ws + 125829120);
  u16* wsVT  = (u16*)(ws + 159383552);   // [8][1024,2048] bf16, 32 MiB
  u16* wsS   = (u16*)(ws + 192937984);   // [8][2048,2048] bf16 P~ = exp(s), 64 MiB
  u16* wsAO  = wsXB;
  u16* wsAO2 = wsQ;
  u16* wsH   = wsK;
  u16* wsHID = wsV;                      // [16384,4096] bf16, 128 MiB (covers V,VT,S)
  u16* wsFFN = wsXB;
  float* wsLINV = (float*)wsQ;           // 64 KiB; Q dead during PV, AO2 written after

  const dim3 tb(32, 8, 1);
  const float inv_sqrt_e = 0.03125f;   // 1/sqrt(1024)
  const float* nf = nullptr;

  // 1) cast x -> bf16
  cast_f32_bf16<<<16384, 256, 0, stream>>>(x, wsXB);

  // 2) weights -> bf16 transposed [N,K]  (Wq/Wk/Wv land contiguous)
  transpose_f32_bf16<<<dim3(32, 32, 1),  tb, 0, stream>>>(Wq, wsWQT, 1024, 1024);
  transpose_f32_bf16<<<dim3(32, 32, 1),  tb, 0, stream>>>(Wk, wsWKT, 1024, 1024);
  transpose_f32_bf16<<<dim3(32, 32, 1),  tb, 0, stream>>>(Wv, wsWVT, 1024, 1024);
  transpose_f32_bf16<<<dim3(32, 32, 1),  tb, 0, stream>>>(Wo, wsWOT, 1024, 1024);
  transpose_f32_bf16<<<dim3(128, 32, 1), tb, 0, stream>>>(W1, wsW1T, 1024, 4096);
  transpose_f32_bf16<<<dim3(32, 128, 1), tb, 0, stream>>>(W2, wsW2T, 4096, 1024);

  // 3) fused QKV: [16384,1024] x [3072,1024]^T, epilogue routes to Q/K/V + bias
  gemm256<5><<<dim3(12, 64, 1), 512, 0, stream>>>(wsXB, wsWQT, wsQ, bq, bk, bv, nf,
                                                  16384, 3072, 1024, 1.f, 0, 0, 0);

  // 4) V -> V^T per batch: [2048,1024] -> [1024,2048]
  transpose_bf16_bf16<<<dim3(32, 64, 8), tb, 0, stream>>>(wsV, wsVT, 2048, 1024, 2048LL * 1024, 1024LL * 2048);

  // 5) P~ = exp(Q K^T / 32) : batched, epilogue exp (no max-sub; |s| <= ~2)
  gemm256<3><<<dim3(8, 8, 8), 512, 0, stream>>>(wsQ, wsK, wsS, nf, nf, nf, nf,
                                                2048, 2048, 1024, inv_sqrt_e,
                                                2048LL * 1024, 2048LL * 1024, 2048LL * 2048);
  // 6) linv[row] = 1 / rowsum(P~)
  rowinv2048<<<16384, 256, 0, stream>>>(wsS, wsLINV);

  // 7) attn_out = (P~ V) * linv : batched, epilogue row-normalize (per-batch linv)
  gemm256<4><<<dim3(4, 8, 8), 512, 0, stream>>>(wsS, wsVT, wsAO, nf, nf, nf, wsLINV,
                                                2048, 1024, 2048, 1.f,
                                                2048LL * 2048, 1024LL * 2048, 2048LL * 1024);
  // 8) out-proj  (AO2 overwrites linv region only after PV completed, stream-ordered)
  gemm256<1><<<dim3(4, 64, 1), 512, 0, stream>>>(wsAO, wsWOT, wsAO2, bo, nf, nf, nf,
                                                 16384, 1024, 1024, 1.f, 0, 0, 0);

  // 9) h = LN(x + AO2)
  ln_add_f32bf16<<<16384, 256, 0, stream>>>(x, wsAO2, g1, b1, wsH);

  // 10) HID = relu(h W1 + bf1) : [16384,1024] x [1024,4096]
  gemm256<2><<<dim3(16, 64, 1), 512, 0, stream>>>(wsH, wsW1T, wsHID, bf1, nf, nf, nf,
                                                  16384, 4096, 1024, 1.f, 0, 0, 0);

  // 11) FFN = HID W2 + bf2 : [16384,4096] x [4096,1024]
  gemm256<1><<<dim3(4, 64, 1), 512, 0, stream>>>(wsHID, wsW2T, wsFFN, bf2, nf, nf, nf,
                                                 16384, 1024, 4096, 1.f, 0, 0, 0);

  // 12) out = LN(h + FFN), fp32
  ln_add_bf16bf16<<<16384, 256, 0, stream>>>(wsH, wsFFN, g2, b2, out);

  (void)in_sizes; (void)n_in; (void)out_size; (void)ws_size;
}